// Round 1
// baseline (194.131 us; speedup 1.0000x reference)
//
#include <hip/hip_runtime.h>
#include <stdint.h>

// Gemma4PatchEmbed on gfx950.
// Stage 1 (prep): pixels -> bf16 A (16384x768, patch-major), w_proj -> bf16 (768x768, already B^T layout),
//                 padding bool -> canonical uint8 mask (runtime width detection).
// Stage 2 (gemm): 128x128 MFMA-bf16 tile GEMM (m97 structure: global_load_lds width=16 staging,
//                 ds_read_b128 fragments, 16x16x32 mfma, 4x4 acc tiles/wave) + fused pos-table gather epilogue.

typedef __attribute__((ext_vector_type(8))) short bfrag_t;      // 8 bf16 (4 VGPRs) MFMA A/B operand
typedef __attribute__((ext_vector_type(4))) float f4_t;          // MFMA C/D
typedef __attribute__((ext_vector_type(8))) unsigned short u16x8;

#define M_TOT 16384
#define K_TOT 768
#define N_TOT 768
#define V_POS 10240

__device__ __forceinline__ unsigned short f2bf(float f) {
    // round-to-nearest-even fp32 -> bf16 (no NaN handling needed here)
    unsigned int u = __float_as_uint(f);
    u += 0x7fffu + ((u >> 16) & 1u);
    return (unsigned short)(u >> 16);
}

__device__ __forceinline__ void async_ld16(const void* g, void* l) {
    // LDS dest = wave-uniform base + lane*16 (gfx950 global_load_lds semantics)
    __builtin_amdgcn_global_load_lds(
        (const __attribute__((address_space(1))) void*)g,
        (__attribute__((address_space(3))) void*)l,
        16, 0, 0);
}

// ---------------------------------------------------------------------------
// Kernel 1: prep.
// blocks [0,6144):   pixel -> A conversion (8 px / thread, float4 reads)
// blocks [6144,6432): w_proj -> bf16 (8 / thread)
// block  6432:       padding mask canonicalization (detect int32 vs uint8 upload)
// ---------------------------------------------------------------------------
__global__ __launch_bounds__(256) void prep_kernel(
    const float* __restrict__ px, const float* __restrict__ wp,
    const void* __restrict__ pad_in,
    unsigned short* __restrict__ A, unsigned short* __restrict__ Wb,
    unsigned char* __restrict__ mask)
{
    int bid = blockIdx.x;
    int tid = threadIdx.x;
    if (bid < 6144) {
        long idx = (long)bid * 256 + tid;          // chunk of 8 pixels along W
        const float4* s = (const float4*)(px + (idx << 3));
        float4 v0 = s[0];
        float4 v1 = s[1];
        int w8 = (int)(idx & 63);                  // 0..63  (W/8)
        int h  = (int)((idx >> 6) & 511);
        int bc = (int)(idx >> 15);                 // b*3 + c
        int c = bc % 3, b = bc / 3;
        int m = b * 1024 + (h >> 4) * 32 + (w8 >> 1);
        int k = c * 256 + (h & 15) * 16 + ((w8 & 1) << 3);
        u16x8 o;
        o[0] = f2bf(2.f * v0.x - 1.f);
        o[1] = f2bf(2.f * v0.y - 1.f);
        o[2] = f2bf(2.f * v0.z - 1.f);
        o[3] = f2bf(2.f * v0.w - 1.f);
        o[4] = f2bf(2.f * v1.x - 1.f);
        o[5] = f2bf(2.f * v1.y - 1.f);
        o[6] = f2bf(2.f * v1.z - 1.f);
        o[7] = f2bf(2.f * v1.w - 1.f);
        *(u16x8*)(A + (long)m * K_TOT + k) = o;
    } else if (bid < 6432) {
        long idx = (long)(bid - 6144) * 256 + tid; // 0..73727
        const float4* s = (const float4*)(wp + (idx << 3));
        float4 v0 = s[0];
        float4 v1 = s[1];
        u16x8 o;
        o[0] = f2bf(v0.x); o[1] = f2bf(v0.y); o[2] = f2bf(v0.z); o[3] = f2bf(v0.w);
        o[4] = f2bf(v1.x); o[5] = f2bf(v1.y); o[6] = f2bf(v1.z); o[7] = f2bf(v1.w);
        *(u16x8*)(Wb + (idx << 3)) = o;
    } else {
        // Detect how the bool array was uploaded. Reading 4096 uints (16 KB) is
        // in-bounds under BOTH interpretations (uint8 buffer = 16 KB, int32 = 64 KB).
        // Random packed uint8 bits => some uint > 1; int32 0/1 data => all <= 1.
        __shared__ int u8mode;
        if (tid == 0) u8mode = 0;
        __syncthreads();
        const unsigned int* pi = (const unsigned int*)pad_in;
        int local = 0;
        for (int i = tid; i < 4096; i += 256)
            if (pi[i] > 1u) local = 1;
        if (local) atomicOr(&u8mode, 1);
        __syncthreads();
        if (u8mode) {
            const unsigned char* p8 = (const unsigned char*)pad_in;
            for (int i = tid; i < M_TOT; i += 256) mask[i] = p8[i];
        } else {
            const int* p32 = (const int*)pad_in;
            for (int i = tid; i < M_TOT; i += 256) mask[i] = (unsigned char)(p32[i] != 0);
        }
    }
}

// ---------------------------------------------------------------------------
// Kernel 2: GEMM (M=16384, N=768, K=768, A row-major K-contig, Wb = B^T row-major
// K-contig) + fused position-embedding gather epilogue. 768 blocks x 256 threads.
// ---------------------------------------------------------------------------
__global__ __launch_bounds__(256) void gemm_kernel(
    const unsigned short* __restrict__ A, const unsigned short* __restrict__ Bt,
    const int* __restrict__ pos_ids, const unsigned char* __restrict__ mask,
    const float* __restrict__ pos_table, float* __restrict__ out)
{
    __shared__ unsigned short As[128 * 32]; // 8 KB
    __shared__ unsigned short Bs[128 * 32]; // 8 KB

    int tid  = threadIdx.x;
    int wave = tid >> 6;
    int lane = tid & 63;
    int bm = blockIdx.x / 6, bn = blockIdx.x % 6;
    int m0 = bm * 128, n0 = bn * 128;

    // staging: each wave fills 2 chunks (16 rows x 64B) of As and of Bs.
    // lane -> (row = lane/4, 16B piece = lane%4), matching LDS dest = base + lane*16.
    int srow = lane >> 2;
    int scol = (lane & 3) << 3;
    int ch0  = wave * 2;
    const unsigned short* ga0 = A  + (size_t)(m0 + ch0 * 16 +      srow) * K_TOT + scol;
    const unsigned short* ga1 = A  + (size_t)(m0 + ch0 * 16 + 16 + srow) * K_TOT + scol;
    const unsigned short* gb0 = Bt + (size_t)(n0 + ch0 * 16 +      srow) * K_TOT + scol;
    const unsigned short* gb1 = Bt + (size_t)(n0 + ch0 * 16 + 16 + srow) * K_TOT + scol;
    unsigned short* la0 = &As[ch0 * 512];
    unsigned short* la1 = &As[ch0 * 512 + 512];
    unsigned short* lb0 = &Bs[ch0 * 512];
    unsigned short* lb1 = &Bs[ch0 * 512 + 512];

    // compute: wave quadrant (64x64), 4x4 tiles of 16x16x32 mfma
    int row_off = (wave & 1) << 6;
    int col_off = (wave >> 1) << 6;
    int fr = lane & 15;          // A row / B col within 16-tile
    int qk = (lane >> 4) << 3;   // k-offset: quad*8

    f4_t acc[4][4] = {};

    for (int kk = 0; kk < K_TOT / 32; ++kk) {
        int k0 = kk * 32;
        async_ld16(ga0 + k0, la0);
        async_ld16(ga1 + k0, la1);
        async_ld16(gb0 + k0, lb0);
        async_ld16(gb1 + k0, lb1);
        __syncthreads();   // compiler drains vmcnt before s_barrier -> LDS tile ready

        bfrag_t a[4], b[4];
#pragma unroll
        for (int i = 0; i < 4; ++i)
            a[i] = *(const bfrag_t*)&As[(row_off + i * 16 + fr) * 32 + qk];
#pragma unroll
        for (int i = 0; i < 4; ++i)
            b[i] = *(const bfrag_t*)&Bs[(col_off + i * 16 + fr) * 32 + qk];
#pragma unroll
        for (int mi = 0; mi < 4; ++mi)
#pragma unroll
            for (int ni = 0; ni < 4; ++ni)
                acc[mi][ni] = __builtin_amdgcn_mfma_f32_16x16x32_bf16(
                    a[mi], b[ni], acc[mi][ni], 0, 0, 0);
        __syncthreads();   // protect LDS from next iteration's staging
    }

    // Epilogue: C/D layout col = lane&15, row = quad*4 + reg (m89/m91-verified).
    int quad = lane >> 4;
#pragma unroll
    for (int mi = 0; mi < 4; ++mi) {
#pragma unroll
        for (int reg = 0; reg < 4; ++reg) {
            int r = m0 + row_off + mi * 16 + quad * 4 + reg;   // global m row
            int xid = pos_ids[2 * r];
            int yid = pos_ids[2 * r + 1];
            xid = xid < 0 ? 0 : xid;
            yid = yid < 0 ? 0 : yid;
            bool p = mask[r] != 0;
            const float* t0 = pos_table + (size_t)xid * N_TOT;
            const float* t1 = pos_table + (size_t)(V_POS + yid) * N_TOT;
            float* orow = out + (size_t)r * N_TOT;
#pragma unroll
            for (int ni = 0; ni < 4; ++ni) {
                int cidx = n0 + col_off + ni * 16 + fr;
                float pos = p ? 0.f : (t0[cidx] + t1[cidx]);
                orow[cidx] = acc[mi][ni][reg] + pos;
            }
        }
    }
}

extern "C" void kernel_launch(void* const* d_in, const int* in_sizes, int n_in,
                              void* d_out, int out_size, void* d_ws, size_t ws_size,
                              hipStream_t stream) {
    const float* px  = (const float*)d_in[0];   // (16,3,512,512)
    const float* wp  = (const float*)d_in[1];   // (768, 768)
    const float* pt  = (const float*)d_in[2];   // (2, 10240, 768)
    const int*   pid = (const int*)d_in[3];     // (16,1024,2)
    const void*  pad = d_in[4];                 // (16,1024) bool (width detected on-device)

    unsigned short* A    = (unsigned short*)d_ws;                 // 16384*768 bf16 = 25.2 MB
    unsigned short* Wb   = A + (size_t)M_TOT * K_TOT;             // 768*768 bf16   = 1.2 MB
    unsigned char*  mask = (unsigned char*)(Wb + (size_t)N_TOT * K_TOT); // 16 KB

    prep_kernel<<<6433, 256, 0, stream>>>(px, wp, pad, A, Wb, mask);
    gemm_kernel<<<(M_TOT / 128) * (N_TOT / 128), 256, 0, stream>>>(
        A, Wb, pid, mask, pt, (float*)d_out);
}